// Round 1
// baseline (1086.313 us; speedup 1.0000x reference)
//
#include <hip/hip_runtime.h>

typedef __attribute__((ext_vector_type(8))) short short8;
typedef __attribute__((ext_vector_type(4))) float floatx4;

#define MFMA(a, b, c) __builtin_amdgcn_mfma_f32_16x16x32_bf16((a), (b), (c), 0, 0, 0)

constexpr int N_NODES = 50000;
constexpr int N_EDGES = 800000;
constexpr int F = 128;
constexpr int XS_STRIDE = 264;  // 256 + 8 bf16 pad: 528B row = 132 dw, %32=4 -> <=2-way bank alias (free)
constexpr int YS_STRIDE = 136;  // 128 + 8 pad: 272B = 68 dw, %32=4
constexpr int EDGE_TILES = N_EDGES / 64;         // 12500 (exact)
constexpr int NODE_TILES = (N_NODES + 63) / 64;  // 782 (last tile 16 rows)

__device__ __forceinline__ unsigned short f2b(float x) {
  // round-to-nearest-even fp32 -> bf16 (matches numpy/jax)
  union { float f; unsigned u; } c; c.f = x;
  unsigned r = c.u + 0x7FFFu + ((c.u >> 16) & 1u);
  return (unsigned short)(r >> 16);
}

// ---- weight prep: fp32 [K][N] -> bf16 [N][K] (so B-frag = 8 contiguous k) ----
__global__ void prep_weights(const float* __restrict__ W1a, const float* __restrict__ W1b,
                             const float* __restrict__ W2a, const float* __restrict__ W2b,
                             unsigned short* __restrict__ wbuf) {
  unsigned short* W1aT = wbuf;           // [128 n][256 k]
  unsigned short* W1bT = wbuf + 32768;   // [128][128]
  unsigned short* W2aT = wbuf + 49152;
  unsigned short* W2bT = wbuf + 65536;
  const int t = blockIdx.x * blockDim.x + threadIdx.x;
  const int stride = gridDim.x * blockDim.x;
  for (int i = t; i < 128 * 256; i += stride) {
    const int n = i >> 8, k = i & 255;
    W1aT[i] = f2b(W1a[k * 128 + n]);
  }
  for (int i = t; i < 128 * 128; i += stride) {
    const int n = i >> 7, k = i & 127;
    W1bT[i] = f2b(W1b[k * 128 + n]);
    W2aT[i] = f2b(W2a[k * 128 + n]);
    W2bT[i] = f2b(W2b[k * 128 + n]);
  }
}

// ---- edge MLP + atomic scatter-sum into agg ----
// Persistent blocks; each 256-thr block processes 64-edge tiles.
// Wave w owns output cols [32w, 32w+32); B-fragments register-resident across tiles.
__global__ __launch_bounds__(256, 3) void edge_mlp_scatter(
    const float* __restrict__ nf, const float* __restrict__ ef,
    const int* __restrict__ src, const int* __restrict__ dst,
    const float* __restrict__ b1a, const float* __restrict__ b1b,
    const unsigned short* __restrict__ W1aT, const unsigned short* __restrict__ W1bT,
    float* __restrict__ agg) {
  __shared__ __align__(16) unsigned short Xs[64 * XS_STRIDE];
  __shared__ __align__(16) unsigned short Ys[64 * YS_STRIDE];
  __shared__ int dstS[64];

  const int tid = threadIdx.x;
  const int wave = tid >> 6;
  const int lane = tid & 63;
  const int l16 = lane & 15;
  const int quad = lane >> 4;
  const int nbase = wave * 32;

  // register-resident B fragments + biases (reused for every tile)
  short8 bfr1[2][8];  // GEMM1: K=256 -> 8 k-steps, 2 n-tiles
  short8 bfr2[2][4];  // GEMM2: K=128 -> 4 k-steps
  float bias1[2], bias2[2];
#pragma unroll
  for (int t = 0; t < 2; ++t) {
    const int n = nbase + t * 16 + l16;
#pragma unroll
    for (int ks = 0; ks < 8; ++ks)
      bfr1[t][ks] = *(const short8*)(W1aT + n * 256 + ks * 32 + quad * 8);
#pragma unroll
    for (int ks = 0; ks < 4; ++ks)
      bfr2[t][ks] = *(const short8*)(W1bT + n * 128 + ks * 32 + quad * 8);
    bias1[t] = b1a[n];
    bias2[t] = b1b[n];
  }

  for (int tile = blockIdx.x; tile < EDGE_TILES; tile += gridDim.x) {
    const int ebase = tile * 64;
    __syncthreads();  // protect Xs/Ys/dstS from previous iteration's readers
    if (tid < 64) dstS[tid] = dst[ebase + tid];
    // stage X = [nf[src[e]] | ef[e]] as bf16; 64 consecutive threads cover one row
#pragma unroll
    for (int i = 0; i < 16; ++i) {
      const int fidx = tid + 256 * i;
      const int r = fidx >> 6;   // edge row in tile
      const int c4 = fidx & 63;  // float4 col (0..31 node, 32..63 edge)
      float4 v;
      if (c4 < 32) {
        const int s = src[ebase + r];
        v = ((const float4*)nf)[(long)s * 32 + c4];
      } else {
        v = ((const float4*)ef)[(long)(ebase + r) * 32 + (c4 - 32)];
      }
      unsigned short* p = &Xs[r * XS_STRIDE + c4 * 4];
      p[0] = f2b(v.x); p[1] = f2b(v.y); p[2] = f2b(v.z); p[3] = f2b(v.w);
    }
    __syncthreads();

    // GEMM1: Y1 = relu(X @ W1a + b1a), X is [64 x 256]
    floatx4 acc[4][2];
#pragma unroll
    for (int mt = 0; mt < 4; ++mt)
#pragma unroll
      for (int t = 0; t < 2; ++t)
        acc[mt][t] = (floatx4){bias1[t], bias1[t], bias1[t], bias1[t]};
#pragma unroll
    for (int ks = 0; ks < 8; ++ks)
#pragma unroll
      for (int mt = 0; mt < 4; ++mt) {
        const short8 a = *(const short8*)(&Xs[(mt * 16 + l16) * XS_STRIDE + ks * 32 + quad * 8]);
        acc[mt][0] = MFMA(a, bfr1[0][ks], acc[mt][0]);
        acc[mt][1] = MFMA(a, bfr1[1][ks], acc[mt][1]);
      }
    // relu -> Ys (bf16, A-layout for GEMM2)
#pragma unroll
    for (int mt = 0; mt < 4; ++mt)
#pragma unroll
      for (int t = 0; t < 2; ++t)
#pragma unroll
        for (int r = 0; r < 4; ++r) {
          const int row = mt * 16 + quad * 4 + r;
          const int col = nbase + t * 16 + l16;
          Ys[row * YS_STRIDE + col] = f2b(fmaxf(acc[mt][t][r], 0.f));
        }
    __syncthreads();

    // GEMM2: M = Y1 @ W1b + b1b, then atomic scatter to agg[dst]
    floatx4 acc2[4][2];
#pragma unroll
    for (int mt = 0; mt < 4; ++mt)
#pragma unroll
      for (int t = 0; t < 2; ++t)
        acc2[mt][t] = (floatx4){bias2[t], bias2[t], bias2[t], bias2[t]};
#pragma unroll
    for (int ks = 0; ks < 4; ++ks)
#pragma unroll
      for (int mt = 0; mt < 4; ++mt) {
        const short8 a = *(const short8*)(&Ys[(mt * 16 + l16) * YS_STRIDE + ks * 32 + quad * 8]);
        acc2[mt][0] = MFMA(a, bfr2[0][ks], acc2[mt][0]);
        acc2[mt][1] = MFMA(a, bfr2[1][ks], acc2[mt][1]);
      }
#pragma unroll
    for (int mt = 0; mt < 4; ++mt)
#pragma unroll
      for (int t = 0; t < 2; ++t)
#pragma unroll
        for (int r = 0; r < 4; ++r) {
          const int row = mt * 16 + quad * 4 + r;
          const int col = nbase + t * 16 + l16;
          unsafeAtomicAdd(&agg[(long)dstS[row] * 128 + col], acc2[mt][t][r]);
        }
  }
}

// ---- node MLP: out = relu((agg + nf) @ W2a + b2a) @ W2b + b2b ----
__global__ __launch_bounds__(256) void node_mlp(
    const float* __restrict__ nf, const float* __restrict__ agg,
    const float* __restrict__ b2a, const float* __restrict__ b2b,
    const unsigned short* __restrict__ W2aT, const unsigned short* __restrict__ W2bT,
    float* __restrict__ out) {
  __shared__ __align__(16) unsigned short Xs[64 * YS_STRIDE];
  __shared__ __align__(16) unsigned short Ys[64 * YS_STRIDE];

  const int tid = threadIdx.x;
  const int wave = tid >> 6;
  const int lane = tid & 63;
  const int l16 = lane & 15;
  const int quad = lane >> 4;
  const int nbase = wave * 32;
  const int rbase = blockIdx.x * 64;

  short8 bfrA[2][4], bfrB[2][4];
  float biasA[2], biasB[2];
#pragma unroll
  for (int t = 0; t < 2; ++t) {
    const int n = nbase + t * 16 + l16;
#pragma unroll
    for (int ks = 0; ks < 4; ++ks) {
      bfrA[t][ks] = *(const short8*)(W2aT + n * 128 + ks * 32 + quad * 8);
      bfrB[t][ks] = *(const short8*)(W2bT + n * 128 + ks * 32 + quad * 8);
    }
    biasA[t] = b2a[n];
    biasB[t] = b2b[n];
  }

  // stage h = agg + nf as bf16 (clamp row for tail tile; stores guarded later)
#pragma unroll
  for (int i = 0; i < 8; ++i) {
    const int fidx = tid + 256 * i;
    const int r = fidx >> 5;
    const int c4 = fidx & 31;
    const long gr = min(rbase + r, N_NODES - 1);
    const float4 a = ((const float4*)agg)[gr * 32 + c4];
    const float4 n = ((const float4*)nf)[gr * 32 + c4];
    unsigned short* p = &Xs[r * YS_STRIDE + c4 * 4];
    p[0] = f2b(a.x + n.x); p[1] = f2b(a.y + n.y);
    p[2] = f2b(a.z + n.z); p[3] = f2b(a.w + n.w);
  }
  __syncthreads();

  floatx4 acc[4][2];
#pragma unroll
  for (int mt = 0; mt < 4; ++mt)
#pragma unroll
    for (int t = 0; t < 2; ++t)
      acc[mt][t] = (floatx4){biasA[t], biasA[t], biasA[t], biasA[t]};
#pragma unroll
  for (int ks = 0; ks < 4; ++ks)
#pragma unroll
    for (int mt = 0; mt < 4; ++mt) {
      const short8 a = *(const short8*)(&Xs[(mt * 16 + l16) * YS_STRIDE + ks * 32 + quad * 8]);
      acc[mt][0] = MFMA(a, bfrA[0][ks], acc[mt][0]);
      acc[mt][1] = MFMA(a, bfrA[1][ks], acc[mt][1]);
    }
#pragma unroll
  for (int mt = 0; mt < 4; ++mt)
#pragma unroll
    for (int t = 0; t < 2; ++t)
#pragma unroll
      for (int r = 0; r < 4; ++r) {
        const int row = mt * 16 + quad * 4 + r;
        const int col = nbase + t * 16 + l16;
        Ys[row * YS_STRIDE + col] = f2b(fmaxf(acc[mt][t][r], 0.f));
      }
  __syncthreads();

  floatx4 acc2[4][2];
#pragma unroll
  for (int mt = 0; mt < 4; ++mt)
#pragma unroll
    for (int t = 0; t < 2; ++t)
      acc2[mt][t] = (floatx4){biasB[t], biasB[t], biasB[t], biasB[t]};
#pragma unroll
  for (int ks = 0; ks < 4; ++ks)
#pragma unroll
    for (int mt = 0; mt < 4; ++mt) {
      const short8 a = *(const short8*)(&Ys[(mt * 16 + l16) * YS_STRIDE + ks * 32 + quad * 8]);
      acc2[mt][0] = MFMA(a, bfrB[0][ks], acc2[mt][0]);
      acc2[mt][1] = MFMA(a, bfrB[1][ks], acc2[mt][1]);
    }
#pragma unroll
  for (int mt = 0; mt < 4; ++mt)
#pragma unroll
    for (int t = 0; t < 2; ++t)
#pragma unroll
      for (int r = 0; r < 4; ++r) {
        const int row = mt * 16 + quad * 4 + r;
        const int grow = rbase + row;
        if (grow < N_NODES) {
          const int col = nbase + t * 16 + l16;
          out[(long)grow * 128 + col] = acc2[mt][t][r];
        }
      }
}

extern "C" void kernel_launch(void* const* d_in, const int* in_sizes, int n_in,
                              void* d_out, int out_size, void* d_ws, size_t ws_size,
                              hipStream_t stream) {
  const float* nf = (const float*)d_in[0];
  const float* ef = (const float*)d_in[1];
  const int* src = (const int*)d_in[2];
  const int* dst = (const int*)d_in[3];
  const float* W1a = (const float*)d_in[4];
  const float* b1a = (const float*)d_in[5];
  const float* W1b = (const float*)d_in[6];
  const float* b1b = (const float*)d_in[7];
  const float* W2a = (const float*)d_in[8];
  const float* b2a = (const float*)d_in[9];
  const float* W2b = (const float*)d_in[10];
  const float* b2b = (const float*)d_in[11];
  float* out = (float*)d_out;

  // workspace layout: agg fp32 [50000*128] then bf16 transposed weights
  float* agg = (float*)d_ws;
  unsigned short* wbuf = (unsigned short*)((char*)d_ws + 25600000);
  const unsigned short* W1aT = wbuf;
  const unsigned short* W1bT = wbuf + 32768;
  const unsigned short* W2aT = wbuf + 49152;
  const unsigned short* W2bT = wbuf + 65536;

  hipMemsetAsync(agg, 0, (size_t)N_NODES * 128 * sizeof(float), stream);
  prep_weights<<<64, 256, 0, stream>>>(W1a, W1b, W2a, W2b, wbuf);
  edge_mlp_scatter<<<768, 256, 0, stream>>>(nf, ef, src, dst, b1a, b1b, W1aT, W1bT, agg);
  node_mlp<<<NODE_TILES, 256, 0, stream>>>(nf, agg, b2a, b2b, W2aT, W2bT, out);
}